// Round 1
// baseline (559.949 us; speedup 1.0000x reference)
//
#include <hip/hip_runtime.h>
#include <cmath>

// KPConv fused kernel for MI355X (gfx950), fp32 vector-ALU path.
// M=50000, H=32, K=15, C_IN=C_OUT=128 (shapes from reference; M taken at runtime).
//
// Per block: 16 query points, 512 threads, 64 KB LDS (static, at the limit).
//   Phase 0: influence[16][32][15] -> LDS (thread = one (point, neighbor) pair)
//   Phase A: wf[m][k][c] accumulated in registers; thread = (point, channel-quad)
//   Phase B: out[16][128] += sum_k wf_k @ W[k]; 4-way k-split, 16 acc/thread
//   Reduce : cross-subset sum in LDS, coalesced float4 store.

constexpr int HN = 32;    // neighbors per query
constexpr int KP = 15;    // kernel points
constexpr int CI = 128;   // input channels
constexpr int CO = 128;   // output channels
constexpr int MB = 16;    // query points per block
constexpr int NT = 512;   // threads per block
constexpr float INV_SIGMA = 0.5f;  // 1/SIGMA, SIGMA=2.0

__global__ __launch_bounds__(NT, 4)
void kpconv_fused(const float* __restrict__ q_pts,
                  const float* __restrict__ s_pts,
                  const float* __restrict__ s_feats,
                  const int*   __restrict__ neighb_inds,
                  const float* __restrict__ weights,
                  const float* __restrict__ kernel_points,
                  float* __restrict__ out,
                  int M)
{
    // 32 KB: influence, padded k-stride 16 for aligned b128 reads
    __shared__ __align__(16) float infl[MB][HN][16];
    // 32 KB multi-use: {inds+qp+kp} in Phase0/A, wf tiles in Phase B, reduce buf at end
    __shared__ __align__(16) float blk2[4 * MB * CI];

    int*   inds = reinterpret_cast<int*>(blk2);         // [MB][HN]   (2048 B)
    float* qp   = blk2 + MB * HN;                        // [MB][3]
    float* kp   = blk2 + MB * HN + MB * 3;               // [KP][3]

    const int t  = threadIdx.x;
    const int m0 = blockIdx.x * MB;

    // ---------------- Phase 0: influences ----------------
    if (t < KP * 3) kp[t] = kernel_points[t];
    if (t < MB * 3) {
        int mb = t / 3;
        int cc = t - mb * 3;
        int r  = m0 + mb;
        qp[t] = (r < M) ? q_pts[r * 3 + cc] : 0.0f;
    }

    const int mb0 = t >> 5;   // 0..15  (point within block)
    const int h0  = t & 31;   // 0..31  (neighbor in Phase 0, channel-quad in Phase A)
    {
        int  r     = m0 + mb0;
        bool valid = (r < M);
        int  idx   = valid ? neighb_inds[r * HN + h0] : 0;
        inds[mb0 * HN + h0] = idx;
        float sx = s_pts[idx * 3 + 0];
        float sy = s_pts[idx * 3 + 1];
        float sz = s_pts[idx * 3 + 2];
        __syncthreads();   // qp/kp staged
        float rx = sx - qp[mb0 * 3 + 0];
        float ry = sy - qp[mb0 * 3 + 1];
        float rz = sz - qp[mb0 * 3 + 2];
        #pragma unroll
        for (int k = 0; k < KP; ++k) {
            float dx = rx - kp[k * 3 + 0];
            float dy = ry - kp[k * 3 + 1];
            float dz = rz - kp[k * 3 + 2];
            float d2 = dx * dx + dy * dy + dz * dz;
            float v  = fmaxf(1.0f - sqrtf(d2) * INV_SIGMA, 0.0f);
            infl[mb0][h0][k] = valid ? v : 0.0f;
        }
        infl[mb0][h0][15] = 0.0f;
    }
    __syncthreads();   // influences + inds visible

    // ---------------- Phase A: wf[k][4] per thread ----------------
    // thread (mb0, cq=h0) owns point mb0, channels cq*4..cq*4+3, all 15 k.
    const int cq = h0;
    float wf[KP][4];
    #pragma unroll
    for (int k = 0; k < KP; ++k) {
        wf[k][0] = 0.0f; wf[k][1] = 0.0f; wf[k][2] = 0.0f; wf[k][3] = 0.0f;
    }

    const float4* feats4 = reinterpret_cast<const float4*>(s_feats);
    #pragma unroll 2
    for (int h = 0; h < HN; ++h) {
        int    idx = inds[mb0 * HN + h];
        float4 f   = feats4[idx * (CI / 4) + cq];
        const float4* i4 = reinterpret_cast<const float4*>(&infl[mb0][h][0]);
        float4 a0 = i4[0], a1 = i4[1], a2 = i4[2], a3 = i4[3];
#define FMA4(kk, s)                                   \
        wf[kk][0] = fmaf((s), f.x, wf[kk][0]);        \
        wf[kk][1] = fmaf((s), f.y, wf[kk][1]);        \
        wf[kk][2] = fmaf((s), f.z, wf[kk][2]);        \
        wf[kk][3] = fmaf((s), f.w, wf[kk][3]);
        FMA4(0,  a0.x) FMA4(1,  a0.y) FMA4(2,  a0.z) FMA4(3,  a0.w)
        FMA4(4,  a1.x) FMA4(5,  a1.y) FMA4(6,  a1.z) FMA4(7,  a1.w)
        FMA4(8,  a2.x) FMA4(9,  a2.y) FMA4(10, a2.z) FMA4(11, a2.w)
        FMA4(12, a3.x) FMA4(13, a3.y) FMA4(14, a3.z)
#undef FMA4
    }
    __syncthreads();   // done reading inds (blk2 about to be overwritten)

    // ---------------- Phase B: out += sum_k wf_k @ W[k] ----------------
    // 512 threads = 4 k-subsets x 128. Subset tile: 16 rows x 128 d,
    // thread = (rq: 4 rows) x (dq: 4 d) -> 16 accumulators.
    const int ks  = t >> 7;        // 0..3
    const int tid = t & 127;
    const int rq  = tid >> 5;      // 0..3
    const int dq  = tid & 31;      // 0..31

    float acc[4][4];
    #pragma unroll
    for (int i = 0; i < 4; ++i) {
        acc[i][0] = 0.0f; acc[i][1] = 0.0f; acc[i][2] = 0.0f; acc[i][3] = 0.0f;
    }

    float* wfl = blk2;   // [4 kslots][MB][CI]

    for (int g = 0; g < 4; ++g) {
        __syncthreads();   // previous reads of blk2 done
        #pragma unroll
        for (int s = 0; s < 4; ++s) {
            int k = g * 4 + s;
            if (k < KP) {
                float4 v = make_float4(wf[k][0], wf[k][1], wf[k][2], wf[k][3]);
                *reinterpret_cast<float4*>(&wfl[(s * MB + mb0) * CI + cq * 4]) = v;
            }
        }
        __syncthreads();   // wf tiles staged
        int k = g * 4 + ks;
        if (k < KP) {
            const float4* Wk = reinterpret_cast<const float4*>(weights) + k * CI * (CO / 4);
            const float*  ab = &wfl[(ks * MB + rq * 4) * CI];
            #pragma unroll 1
            for (int c4 = 0; c4 < CI / 4; ++c4) {
                float4 a0 = *reinterpret_cast<const float4*>(ab + 0 * CI + c4 * 4);
                float4 a1 = *reinterpret_cast<const float4*>(ab + 1 * CI + c4 * 4);
                float4 a2 = *reinterpret_cast<const float4*>(ab + 2 * CI + c4 * 4);
                float4 a3 = *reinterpret_cast<const float4*>(ab + 3 * CI + c4 * 4);
                float4 w0 = Wk[(c4 * 4 + 0) * (CO / 4) + dq];
                float4 w1 = Wk[(c4 * 4 + 1) * (CO / 4) + dq];
                float4 w2 = Wk[(c4 * 4 + 2) * (CO / 4) + dq];
                float4 w3 = Wk[(c4 * 4 + 3) * (CO / 4) + dq];
#define ACCJ(i, AX, W)                                \
                acc[i][0] = fmaf((AX), W.x, acc[i][0]); \
                acc[i][1] = fmaf((AX), W.y, acc[i][1]); \
                acc[i][2] = fmaf((AX), W.z, acc[i][2]); \
                acc[i][3] = fmaf((AX), W.w, acc[i][3]);
                ACCJ(0, a0.x, w0) ACCJ(0, a0.y, w1) ACCJ(0, a0.z, w2) ACCJ(0, a0.w, w3)
                ACCJ(1, a1.x, w0) ACCJ(1, a1.y, w1) ACCJ(1, a1.z, w2) ACCJ(1, a1.w, w3)
                ACCJ(2, a2.x, w0) ACCJ(2, a2.y, w1) ACCJ(2, a2.z, w2) ACCJ(2, a2.w, w3)
                ACCJ(3, a3.x, w0) ACCJ(3, a3.y, w1) ACCJ(3, a3.z, w2) ACCJ(3, a3.w, w3)
#undef ACCJ
            }
        }
    }

    // ---------------- Reduce across k-subsets, store ----------------
    __syncthreads();   // last GEMM reads of blk2 done
    float* red = blk2;   // [4][MB*CO] = 32 KB
    #pragma unroll
    for (int i = 0; i < 4; ++i) {
        int o = (rq * 4 + i) * CO + dq * 4;
        *reinterpret_cast<float4*>(&red[ks * (MB * CO) + o]) =
            make_float4(acc[i][0], acc[i][1], acc[i][2], acc[i][3]);
    }
    __syncthreads();
    const float4* red4 = reinterpret_cast<const float4*>(red);
    float4 s0 = red4[0 * (MB * CO / 4) + t];
    float4 s1 = red4[1 * (MB * CO / 4) + t];
    float4 s2 = red4[2 * (MB * CO / 4) + t];
    float4 s3 = red4[3 * (MB * CO / 4) + t];
    float4 r;
    r.x = s0.x + s1.x + s2.x + s3.x;
    r.y = s0.y + s1.y + s2.y + s3.y;
    r.z = s0.z + s1.z + s2.z + s3.z;
    r.w = s0.w + s1.w + s2.w + s3.w;
    int row = t >> 5;   // output row within block (t*4 / 128)
    if (m0 + row < M) {
        reinterpret_cast<float4*>(out)[(m0 + row) * (CO / 4) + (t & 31)] = r;
    }
}

extern "C" void kernel_launch(void* const* d_in, const int* in_sizes, int n_in,
                              void* d_out, int out_size, void* d_ws, size_t ws_size,
                              hipStream_t stream)
{
    const float* q_pts         = (const float*)d_in[0];
    const float* s_pts         = (const float*)d_in[1];
    const float* s_feats       = (const float*)d_in[2];
    const int*   neighb_inds   = (const int*)d_in[3];
    const float* weights       = (const float*)d_in[4];
    const float* kernel_points = (const float*)d_in[5];
    float*       out           = (float*)d_out;

    int M    = in_sizes[0] / 3;
    int grid = (M + MB - 1) / MB;
    hipLaunchKernelGGL(kpconv_fused, dim3(grid), dim3(NT), 0, stream,
                       q_pts, s_pts, s_feats, neighb_inds, weights, kernel_points, out, M);
}

// Round 2
// 323.024 us; speedup vs baseline: 1.7335x; 1.7335x over previous
//
#include <hip/hip_runtime.h>
#include <cmath>

// KPConv fused, round 2: phase A (influence x neighbor-feature aggregation) on
// fp32 VALU (proven correct R1), phase B (wf @ W, 24.6 GF) on bf16 MFMA with
// hi/lo split precision (AhBh + AhBl + AlBh; lo*lo dropped, ~2^-18 rel error).
//
// Block: 32 query points, 1024 threads (16 waves), 64 KB static LDS pool:
//   phase 0: infl[32 pts][32 h][16 k] f32            (64 KB)
//   stage 2: 4 k-slabs of wf as bf16 hi/lo planes    (4 x 16 KB), XOR-swizzled
//   reduce : redbuf[4 kq][32 pts][128 d] f32         (64 KB)
// W is pre-packed by a prep kernel into MFMA-B-fragment order (hi/lo) in d_ws.

constexpr int HN = 32;    // neighbors
constexpr int KP = 15;    // kernel points
constexpr int CI = 128;   // in channels
constexpr int CO = 128;   // out channels
constexpr int MB = 32;    // points per block
constexpr int NT = 1024;  // threads per block
constexpr float INV_SIGMA = 0.5f;

using short8 = __attribute__((ext_vector_type(8))) short;
using f32x4  = __attribute__((ext_vector_type(4))) float;

static __device__ __forceinline__ unsigned short f2bf(float x) {
    unsigned u = __float_as_uint(x);
    u += 0x7fff + ((u >> 16) & 1);          // round-to-nearest-even
    return (unsigned short)(u >> 16);
}
static __device__ __forceinline__ float bf2f(unsigned short h) {
    return __uint_as_float(((unsigned)h) << 16);
}

// ---- prep: pack W[15][128][128] fp32 -> bf16 hi/lo MFMA-B fragments in ws ----
// fragblock fb = (k*4 + s)*8 + dt  (s: 32-chan step, dt: 16-d tile), 480 total.
// Layout (ushort elems): fb*1024 + plane*512 + lane*8 + j, 16B/lane coalesced.
// B-frag semantics: lane l elem j = W[k][c = s*32 + (l>>4)*8 + j][d = dt*16 + (l&15)]
__global__ void kpconv_prep_w(const float* __restrict__ w,
                              unsigned short* __restrict__ ws16) {
    int t = blockIdx.x * blockDim.x + threadIdx.x;
    int fb = t >> 6, lane = t & 63;
    if (fb >= 480) return;
    int k = fb >> 5, s = (fb >> 3) & 3, dt = fb & 7;
    int g = lane >> 4, n = lane & 15;
    unsigned short* base = ws16 + fb * 1024 + lane * 8;
    #pragma unroll
    for (int j = 0; j < 8; ++j) {
        int c = s * 32 + g * 8 + j;
        int d = dt * 16 + n;
        float v = w[(k * CI + c) * CO + d];
        unsigned short hi = f2bf(v);
        unsigned short lo = f2bf(v - bf2f(hi));
        base[j]       = (short)hi;
        base[512 + j] = (short)lo;
    }
}

#define MFMA(a, b, c) c = __builtin_amdgcn_mfma_f32_16x16x32_bf16(a, b, c, 0, 0, 0)

__global__ __launch_bounds__(NT, 4)
void kpconv_main(const float* __restrict__ q_pts,
                 const float* __restrict__ s_pts,
                 const float* __restrict__ s_feats,
                 const int*   __restrict__ nb,
                 const float* __restrict__ kpts,
                 const unsigned short* __restrict__ wfr,
                 float* __restrict__ out, int M)
{
    __shared__ __align__(16) char pool[65536];
    float* infl = (float*)pool;              // [32][32][16] f32 during phase 0/A

    const int t  = threadIdx.x;
    const int m0 = blockIdx.x * MB;

    // ---------------- phase 0: influences ----------------
    {
        int p = t >> 5, h = t & 31;
        int r = m0 + p;
        bool valid = (r < M);
        int rr = valid ? r : 0;
        int idx = nb[rr * HN + h];
        float sx = s_pts[idx * 3 + 0], sy = s_pts[idx * 3 + 1], sz = s_pts[idx * 3 + 2];
        float qx = q_pts[rr * 3 + 0],  qy = q_pts[rr * 3 + 1],  qz = q_pts[rr * 3 + 2];
        float rx = sx - qx, ry = sy - qy, rz = sz - qz;
        float vals[16];
        #pragma unroll
        for (int k = 0; k < KP; ++k) {
            float dx = rx - kpts[k * 3 + 0];
            float dy = ry - kpts[k * 3 + 1];
            float dz = rz - kpts[k * 3 + 2];
            float d2 = dx * dx + dy * dy + dz * dz;
            float v  = fmaxf(1.0f - sqrtf(d2) * INV_SIGMA, 0.0f);
            vals[k] = valid ? v : 0.0f;
        }
        vals[15] = 0.0f;
        float4* dst = (float4*)(infl + (p * 32 + h) * 16);
        dst[0] = make_float4(vals[0],  vals[1],  vals[2],  vals[3]);
        dst[1] = make_float4(vals[4],  vals[5],  vals[6],  vals[7]);
        dst[2] = make_float4(vals[8],  vals[9],  vals[10], vals[11]);
        dst[3] = make_float4(vals[12], vals[13], vals[14], vals[15]);
    }
    __syncthreads();

    // ---------------- phase A: wf[15][4] per thread (fp32 VALU) ----------------
    const int p  = t >> 5;    // point in block
    const int cq = t & 31;    // channel quad
    float wf[KP][4];
    #pragma unroll
    for (int k = 0; k < KP; ++k) { wf[k][0]=0.f; wf[k][1]=0.f; wf[k][2]=0.f; wf[k][3]=0.f; }

    {
        int r = m0 + p;
        int rr = (r < M) ? r : 0;
        const int* nbrow = nb + rr * HN;
        const float4* f4 = (const float4*)s_feats;
        #pragma unroll 2
        for (int h = 0; h < HN; ++h) {
            int idx = nbrow[h];
            float4 f = f4[idx * (CI / 4) + cq];
            const float4* iv = (const float4*)(infl + (p * 32 + h) * 16);
            float4 a0 = iv[0], a1 = iv[1], a2 = iv[2], a3 = iv[3];
#define FMA4(kk, s)                               \
            wf[kk][0] = fmaf((s), f.x, wf[kk][0]); \
            wf[kk][1] = fmaf((s), f.y, wf[kk][1]); \
            wf[kk][2] = fmaf((s), f.z, wf[kk][2]); \
            wf[kk][3] = fmaf((s), f.w, wf[kk][3]);
            FMA4(0,  a0.x) FMA4(1,  a0.y) FMA4(2,  a0.z) FMA4(3,  a0.w)
            FMA4(4,  a1.x) FMA4(5,  a1.y) FMA4(6,  a1.z) FMA4(7,  a1.w)
            FMA4(8,  a2.x) FMA4(9,  a2.y) FMA4(10, a2.z) FMA4(11, a2.w)
            FMA4(12, a3.x) FMA4(13, a3.y) FMA4(14, a3.z)
#undef FMA4
        }
    }

    // ---------------- stage 2: out += sum_k wf_k @ W_k  (bf16 MFMA, hi/lo) ----
    // slab slot kk (16384B): hi plane [32 pts][128 c] bf16 @ +0, lo @ +8192.
    // XOR-swizzle ^((row&7)<<4) on the linear in-plane byte offset.
    const int lane = t & 63;
    const int wid  = t >> 6;        // 0..15
    const int dh   = wid & 3;       // d-half: d-tiles {2dh, 2dh+1}
    const int kq   = wid >> 2;      // k-quarter: k in {kq, 4+kq, 8+kq, 12+kq}
    const int g    = lane >> 4;     // k-group within fragment
    const int n16  = lane & 15;

    f32x4 acc[2][2] = {};           // [mt][dti]

    #pragma unroll
    for (int kb = 0; kb < 4; ++kb) {
        __syncthreads();            // previous pool use done (phase A / prior kb)
        // write 4 k-slabs (wf -> bf16 hi/lo)
        #pragma unroll
        for (int kk = 0; kk < 4; ++kk) {
            int k = kb * 4 + kk;
            if (k < KP) {
                unsigned short h0 = f2bf(wf[k][0]), h1 = f2bf(wf[k][1]);
                unsigned short h2 = f2bf(wf[k][2]), h3 = f2bf(wf[k][3]);
                unsigned short l0 = f2bf(wf[k][0] - bf2f(h0));
                unsigned short l1 = f2bf(wf[k][1] - bf2f(h1));
                unsigned short l2 = f2bf(wf[k][2] - bf2f(h2));
                unsigned short l3 = f2bf(wf[k][3] - bf2f(h3));
                int lin = p * 256 + cq * 8;
                lin ^= (p & 7) << 4;
                uint2 hv, lv;
                hv.x = (unsigned)h0 | ((unsigned)h1 << 16);
                hv.y = (unsigned)h2 | ((unsigned)h3 << 16);
                lv.x = (unsigned)l0 | ((unsigned)l1 << 16);
                lv.y = (unsigned)l2 | ((unsigned)l3 << 16);
                *(uint2*)(pool + kk * 16384 +        lin) = hv;
                *(uint2*)(pool + kk * 16384 + 8192 + lin) = lv;
            }
        }
        __syncthreads();            // slabs ready
        int k = kb * 4 + kq;
        if (k < KP) {
            #pragma unroll
            for (int s = 0; s < 4; ++s) {
                short8 ah[2], al[2];
                #pragma unroll
                for (int mt = 0; mt < 2; ++mt) {
                    int row = mt * 16 + n16;
                    int lin = row * 256 + s * 64 + g * 16;
                    lin ^= (row & 7) << 4;
                    ah[mt] = *(const short8*)(pool + kq * 16384 +        lin);
                    al[mt] = *(const short8*)(pool + kq * 16384 + 8192 + lin);
                }
                const unsigned short* fb0 = wfr + (((k * 4 + s) * 8 + dh * 2) * 1024) + lane * 8;
                short8 bh0 = *(const short8*)(fb0);
                short8 bl0 = *(const short8*)(fb0 + 512);
                short8 bh1 = *(const short8*)(fb0 + 1024);
                short8 bl1 = *(const short8*)(fb0 + 1536);
                MFMA(ah[0], bh0, acc[0][0]);
                MFMA(ah[0], bl0, acc[0][0]);
                MFMA(al[0], bh0, acc[0][0]);
                MFMA(ah[0], bh1, acc[0][1]);
                MFMA(ah[0], bl1, acc[0][1]);
                MFMA(al[0], bh1, acc[0][1]);
                MFMA(ah[1], bh0, acc[1][0]);
                MFMA(ah[1], bl0, acc[1][0]);
                MFMA(al[1], bh0, acc[1][0]);
                MFMA(ah[1], bh1, acc[1][1]);
                MFMA(ah[1], bl1, acc[1][1]);
                MFMA(al[1], bh1, acc[1][1]);
            }
        }
    }

    // ---------------- cross-kq reduce + store ----------------
    __syncthreads();                 // all slab reads done; pool -> redbuf
    float* red = (float*)pool;       // [4 kq][32 pts][128 d]  (64 KB)
    #pragma unroll
    for (int mt = 0; mt < 2; ++mt) {
        #pragma unroll
        for (int dti = 0; dti < 2; ++dti) {
            #pragma unroll
            for (int q = 0; q < 4; ++q) {
                int row = mt * 16 + g * 4 + q;
                int col = (dh * 2 + dti) * 16 + n16;
                red[(kq * 32 + row) * 128 + col] = acc[mt][dti][q];
            }
        }
    }
    __syncthreads();
    {
        int op = t >> 5, od = t & 31;   // point, d-quad
        const float4* r4 = (const float4*)red;
        float4 s0 = r4[(0 * 32 + op) * 32 + od];
        float4 s1 = r4[(1 * 32 + op) * 32 + od];
        float4 s2 = r4[(2 * 32 + op) * 32 + od];
        float4 s3 = r4[(3 * 32 + op) * 32 + od];
        float4 rv;
        rv.x = s0.x + s1.x + s2.x + s3.x;
        rv.y = s0.y + s1.y + s2.y + s3.y;
        rv.z = s0.z + s1.z + s2.z + s3.z;
        rv.w = s0.w + s1.w + s2.w + s3.w;
        if (m0 + op < M)
            ((float4*)out)[(m0 + op) * (CO / 4) + od] = rv;
    }
}

extern "C" void kernel_launch(void* const* d_in, const int* in_sizes, int n_in,
                              void* d_out, int out_size, void* d_ws, size_t ws_size,
                              hipStream_t stream)
{
    const float* q_pts   = (const float*)d_in[0];
    const float* s_pts   = (const float*)d_in[1];
    const float* s_feats = (const float*)d_in[2];
    const int*   nb      = (const int*)d_in[3];
    const float* weights = (const float*)d_in[4];
    const float* kpts    = (const float*)d_in[5];
    float*       out     = (float*)d_out;
    unsigned short* wpak = (unsigned short*)d_ws;   // 983040 bytes used

    int M = in_sizes[0] / 3;

    hipLaunchKernelGGL(kpconv_prep_w, dim3(120), dim3(256), 0, stream, weights, wpak);

    int grid = (M + MB - 1) / MB;
    hipLaunchKernelGGL(kpconv_main, dim3(grid), dim3(NT), 0, stream,
                       q_pts, s_pts, s_feats, nb, kpts, wpak, out, M);
}

// Round 3
// 305.537 us; speedup vs baseline: 1.8327x; 1.0572x over previous
//
#include <hip/hip_runtime.h>
#include <cmath>

// KPConv round 3: both einsums on bf16 MFMA (hi/lo 3-term split precision).
//
// Phase A (per point, one 16x16x32 MFMA per c-tile x 3 terms):
//   A-frag = influence, COMPUTED IN-LANE in fragment layout (lane l owns
//   k-row l&15, h-cols (l>>4)*8..+7) -- no LDS, no transpose, no phase 0.
//   B-frag = neighbor feats gathered straight into registers
//   (lane l elem j = feats[idx[8g+j]][ct*16+(l&15)], 64B segments).
//   D (lane l, reg r) = wf[k=4g+r][c=ct*16+(l&15)] accumulates in accA[2][8].
// Phase B (R2-validated slab GEMM): 4 rounds; round t writes k=4g+t from acc
//   component t (all 64 lanes active), slab g; XOR swizzle (c2^(slab<<5))^((row&7)<<4).
//   16 waves = kq(4) x dh(4); 12 MFMA per (sc) vs pre-packed W-fragments in ws.
// Reduce: cross-kq in LDS, float4 store.

constexpr int HN = 32;
constexpr int KP = 15;
constexpr int CI = 128;
constexpr int CO = 128;
constexpr int MB = 32;    // points per block
constexpr int NT = 1024;  // 16 waves
constexpr float INV_SIGMA = 0.5f;

using short8 = __attribute__((ext_vector_type(8))) short;
using f32x4  = __attribute__((ext_vector_type(4))) float;

static __device__ __forceinline__ unsigned short f2bf(float x) {
    unsigned u = __float_as_uint(x);
    u += 0x7fff + ((u >> 16) & 1);          // RNE
    return (unsigned short)(u >> 16);
}
static __device__ __forceinline__ float bf2f(unsigned short h) {
    return __uint_as_float(((unsigned)h) << 16);
}

// ---- prep: W[15][128][128] f32 -> bf16 hi/lo MFMA-B fragments (R2-verified) ----
// fb = (k*4 + s)*8 + dt; ushort layout fb*1024 + plane*512 + lane*8 + j.
// lane l elem j = W[k][c = s*32 + (l>>4)*8 + j][d = dt*16 + (l&15)]
__global__ void kpconv_prep_w(const float* __restrict__ w,
                              unsigned short* __restrict__ ws16) {
    int t = blockIdx.x * blockDim.x + threadIdx.x;
    int fb = t >> 6, lane = t & 63;
    if (fb >= 480) return;
    int k = fb >> 5, s = (fb >> 3) & 3, dt = fb & 7;
    int g = lane >> 4, n = lane & 15;
    unsigned short* base = ws16 + fb * 1024 + lane * 8;
    #pragma unroll
    for (int j = 0; j < 8; ++j) {
        int c = s * 32 + g * 8 + j;
        int d = dt * 16 + n;
        float v = w[(k * CI + c) * CO + d];
        unsigned short hi = f2bf(v);
        unsigned short lo = f2bf(v - bf2f(hi));
        base[j]       = (short)hi;
        base[512 + j] = (short)lo;
    }
}

#define MFMA(a, b, c) c = __builtin_amdgcn_mfma_f32_16x16x32_bf16(a, b, c, 0, 0, 0)

__global__ __launch_bounds__(NT)
void kpconv_main(const float* __restrict__ q_pts,
                 const float* __restrict__ s_pts,
                 const float* __restrict__ s_feats,
                 const int*   __restrict__ nb,
                 const float* __restrict__ kpts,
                 const unsigned short* __restrict__ wfr,
                 float* __restrict__ out, int M)
{
    __shared__ __align__(16) char pool[65536];

    const int t    = threadIdx.x;
    const int lane = t & 63;
    const int wid  = t >> 6;        // 0..15
    const int g    = lane >> 4;     // 0..3
    const int kk   = lane & 15;     // k-row in phase A frags; n16 elsewhere
    const int m0   = blockIdx.x * MB;

    // this lane's kernel point (k-row kk); row 15 forced to zero influence
    const float kx = kpts[kk * 3 + 0];
    const float ky = kpts[kk * 3 + 1];
    const float kz = kpts[kk * 3 + 2];

    f32x4 accA[2][8] = {};   // wf: lane holds rows k=4g+r, col c=ct*16+kk

    // ================= Phase A =================
    #pragma unroll
    for (int pi = 0; pi < 2; ++pi) {
        const int  gp    = m0 + wid * 2 + pi;
        const bool valid = (gp < M);
        const int  rr    = valid ? gp : 0;
        const float qx = q_pts[rr * 3 + 0];
        const float qy = q_pts[rr * 3 + 1];
        const float qz = q_pts[rr * 3 + 2];

        int idx[8];
        #pragma unroll
        for (int j = 0; j < 8; ++j) idx[j] = nb[rr * HN + g * 8 + j];

        // influence A-fragments (hi/lo), computed in fragment layout
        short8 Ih, Il;
        #pragma unroll
        for (int j = 0; j < 8; ++j) {
            const float* sp = s_pts + idx[j] * 3;
            float rx = sp[0] - qx, ry = sp[1] - qy, rz = sp[2] - qz;
            float dx = rx - kx, dy = ry - ky, dz = rz - kz;
            float d2 = dx * dx + dy * dy + dz * dz;
            float v  = fmaxf(1.0f - sqrtf(d2) * INV_SIGMA, 0.0f);
            if (kk == 15 || !valid) v = 0.0f;
            unsigned short hi = f2bf(v);
            Ih[j] = (short)hi;
            Il[j] = (short)f2bf(v - bf2f(hi));
        }

        // gather feats B-frags + 3-term MFMA per c-tile
        #pragma unroll
        for (int ct = 0; ct < 8; ++ct) {
            float f[8];
            #pragma unroll
            for (int j = 0; j < 8; ++j)
                f[j] = s_feats[idx[j] * CI + ct * 16 + kk];
            short8 Fh, Fl;
            #pragma unroll
            for (int j = 0; j < 8; ++j) {
                unsigned short hi = f2bf(f[j]);
                Fh[j] = (short)hi;
                Fl[j] = (short)f2bf(f[j] - bf2f(hi));
            }
            MFMA(Ih, Fh, accA[pi][ct]);
            MFMA(Ih, Fl, accA[pi][ct]);
            MFMA(Il, Fh, accA[pi][ct]);
        }
    }

    // ================= Phase B =================
    const int kq = wid >> 2;    // k-quarter (slab id)
    const int dh = wid & 3;     // d-tiles {2dh, 2dh+1}
    f32x4 accB[2][2] = {};

    // lds addr: slab*16384 + plane*8192 + row*256 + ((c2 ^ (slab<<5)) ^ ((row&7)<<4))
    #pragma unroll
    for (int tr = 0; tr < 4; ++tr) {
        if (tr) __syncthreads();        // previous round's slab reads done
        // --- write slabs: k = 4g + tr (slab g), value = acc component tr ---
        #pragma unroll
        for (int pi = 0; pi < 2; ++pi) {
            const int prow = wid * 2 + pi;
            char* rowbase = pool + g * 16384 + prow * 256;
            const int rowx = (prow & 7) << 4;
            #pragma unroll
            for (int ct = 0; ct < 8; ++ct) {
                float v = accA[pi][ct][tr];
                unsigned short hi = f2bf(v);
                unsigned short lo = f2bf(v - bf2f(hi));
                int c2  = (ct * 16 + kk) * 2;
                int off = (c2 ^ (g << 5)) ^ rowx;
                *(unsigned short*)(rowbase + off)        = hi;
                *(unsigned short*)(rowbase + 8192 + off) = lo;
            }
        }
        __syncthreads();                // slabs ready
        // --- MFMA: k = 4*kq + tr against pre-packed W fragments ---
        const int k = 4 * kq + tr;
        if (k < KP) {
            #pragma unroll
            for (int sc = 0; sc < 4; ++sc) {
                short8 ah[2], al[2];
                #pragma unroll
                for (int mt = 0; mt < 2; ++mt) {
                    int row = mt * 16 + kk;
                    int c2  = sc * 64 + g * 16;
                    int off = (c2 ^ (kq << 5)) ^ ((row & 7) << 4);
                    const char* base = pool + kq * 16384 + row * 256 + off;
                    ah[mt] = *(const short8*)(base);
                    al[mt] = *(const short8*)(base + 8192);
                }
                const unsigned short* fb0 =
                    wfr + ((k * 4 + sc) * 8 + dh * 2) * 1024 + lane * 8;
                short8 bh0 = *(const short8*)(fb0);
                short8 bl0 = *(const short8*)(fb0 + 512);
                short8 bh1 = *(const short8*)(fb0 + 1024);
                short8 bl1 = *(const short8*)(fb0 + 1536);
                MFMA(ah[0], bh0, accB[0][0]);
                MFMA(ah[0], bl0, accB[0][0]);
                MFMA(al[0], bh0, accB[0][0]);
                MFMA(ah[0], bh1, accB[0][1]);
                MFMA(ah[0], bl1, accB[0][1]);
                MFMA(al[0], bh1, accB[0][1]);
                MFMA(ah[1], bh0, accB[1][0]);
                MFMA(ah[1], bl0, accB[1][0]);
                MFMA(al[1], bh0, accB[1][0]);
                MFMA(ah[1], bh1, accB[1][1]);
                MFMA(ah[1], bl1, accB[1][1]);
                MFMA(al[1], bh1, accB[1][1]);
            }
        }
    }

    // ================= cross-kq reduce + store =================
    __syncthreads();                    // all slab reads done; pool -> redbuf
    float* red = (float*)pool;          // [4 kq][32 p][128 d] f32 = 64 KB
    #pragma unroll
    for (int mt = 0; mt < 2; ++mt) {
        #pragma unroll
        for (int dti = 0; dti < 2; ++dti) {
            #pragma unroll
            for (int q = 0; q < 4; ++q) {
                int row = mt * 16 + g * 4 + q;
                int col = (dh * 2 + dti) * 16 + kk;
                red[(kq * 32 + row) * 128 + col] = accB[mt][dti][q];
            }
        }
    }
    __syncthreads();
    {
        int op = t >> 5, od = t & 31;
        const float4* r4 = (const float4*)red;
        float4 s0 = r4[(0 * 32 + op) * 32 + od];
        float4 s1 = r4[(1 * 32 + op) * 32 + od];
        float4 s2 = r4[(2 * 32 + op) * 32 + od];
        float4 s3 = r4[(3 * 32 + op) * 32 + od];
        float4 rv;
        rv.x = s0.x + s1.x + s2.x + s3.x;
        rv.y = s0.y + s1.y + s2.y + s3.y;
        rv.z = s0.z + s1.z + s2.z + s3.z;
        rv.w = s0.w + s1.w + s2.w + s3.w;
        if (m0 + op < M)
            ((float4*)out)[(m0 + op) * (CO / 4) + od] = rv;
    }
}

extern "C" void kernel_launch(void* const* d_in, const int* in_sizes, int n_in,
                              void* d_out, int out_size, void* d_ws, size_t ws_size,
                              hipStream_t stream)
{
    const float* q_pts   = (const float*)d_in[0];
    const float* s_pts   = (const float*)d_in[1];
    const float* s_feats = (const float*)d_in[2];
    const int*   nb      = (const int*)d_in[3];
    const float* weights = (const float*)d_in[4];
    const float* kpts    = (const float*)d_in[5];
    float*       out     = (float*)d_out;
    unsigned short* wpak = (unsigned short*)d_ws;   // 983040 B of workspace

    int M = in_sizes[0] / 3;

    hipLaunchKernelGGL(kpconv_prep_w, dim3(120), dim3(256), 0, stream, weights, wpak);

    int grid = (M + MB - 1) / MB;
    hipLaunchKernelGGL(kpconv_main, dim3(grid), dim3(NT), 0, stream,
                       q_pts, s_pts, s_feats, nb, kpts, wpak, out, M);
}